// Round 9
// baseline (857.518 us; speedup 1.0000x reference)
//
#include <hip/hip_runtime.h>
#include <hip/hip_fp8.h>
#include <stdint.h>

#define N 2560
#define NSUP 640
#define NQ 1920
#define NCLS 128
#define DF 8192
#define TITER 16
#define EPSF 2.220446049250313e-16f

typedef __attribute__((ext_vector_type(8))) short bf16x8;
typedef __attribute__((ext_vector_type(4))) float f32x4;

// ---------- helpers ----------
__device__ __forceinline__ unsigned short f2bf(float f) {
  unsigned u = __float_as_uint(f);
  return (unsigned short)((u + 0x7FFFu + ((u >> 16) & 1u)) >> 16);  // RNE
}
__device__ __forceinline__ float bf2f(unsigned short h) {
  return __uint_as_float(((unsigned)h) << 16);
}
__device__ __forceinline__ unsigned char f2e4m3(float f) {
  __hip_fp8_e4m3 h(f);                 // OCP e4m3fn on gfx950
  return (unsigned char)h.__x;
}
__device__ __forceinline__ unsigned sortkey(float f) {
  unsigned u = __float_as_uint(f);
  return (u & 0x80000000u) ? ~u : (u | 0x80000000u);
}
__device__ __forceinline__ void load_lds16(const void* g, void* l) {
  __builtin_amdgcn_global_load_lds((const __attribute__((address_space(1))) void*)g,
                                   (__attribute__((address_space(3))) void*)l, 16, 0, 0);
}

// ---------- 1. fp32 -> fp8 copy + row sumsq + rho table ----------
__global__ void k_prep(const float* __restrict__ feats, unsigned char* __restrict__ fb8,
                       float* __restrict__ sq, const float* __restrict__ alpha,
                       float* __restrict__ rho_tab) {
  int i = blockIdx.x, t = threadIdx.x;
  const float4* src = (const float4*)(feats + (size_t)i * DF);
  uchar4* dst = (uchar4*)(fb8 + (size_t)i * DF);
  float s = 0.f;
#pragma unroll
  for (int it = 0; it < 8; ++it) {
    float4 v = src[it * 256 + t];
    s = fmaf(v.x, v.x, s); s = fmaf(v.y, v.y, s);
    s = fmaf(v.z, v.z, s); s = fmaf(v.w, v.w, s);
    uchar4 o; o.x = f2e4m3(v.x); o.y = f2e4m3(v.y); o.z = f2e4m3(v.z); o.w = f2e4m3(v.w);
    dst[it * 256 + t] = o;
  }
  __shared__ float red[256];
  red[t] = s; __syncthreads();
  for (int o = 128; o > 0; o >>= 1) { if (t < o) red[t] += red[t + o]; __syncthreads(); }
  if (t == 0) sq[i] = red[0];
  if (i == 0 && t == 0) {  // Chebyshev rho recurrence (theta=1, delta=alpha)
    float a = alpha[0];
    float rho = a; rho_tab[0] = rho;
    for (int k2 = 1; k2 < 128; ++k2) { rho = 1.f / (2.f / a - rho); rho_tab[k2] = rho; }
  }
}

// ---------- 2. C = fb8 @ fb8^T (fp8 MFMA), sym-half + split-K x2, bf16 out ----------
__global__ __launch_bounds__(256, 2) void k_gemm(const unsigned char* __restrict__ fb8,
                                                 unsigned short* __restrict__ C0,
                                                 unsigned short* __restrict__ C1) {
  __shared__ __align__(16) unsigned char As[128 * 64];
  __shared__ __align__(16) unsigned char Bs[128 * 64];
  int bid = blockIdx.x;
  int ks = bid >= 210;
  int tid2 = bid - 210 * ks;
  unsigned short* Cd = ks ? C1 : C0;
  const int kbase = ks << 12;
  int bx = (int)((sqrtf(8.0f * (float)tid2 + 1.0f) - 1.0f) * 0.5f);
  while ((bx + 1) * (bx + 2) / 2 <= tid2) ++bx;
  while (bx * (bx + 1) / 2 > tid2) --bx;
  int by = tid2 - bx * (bx + 1) / 2;           // by <= bx
  const int rA = by * 128, rB = bx * 128;
  const int t = threadIdx.x, w = t >> 6, l = t & 63;
  const int q = l >> 4, m = l & 15;
  const int wr = w >> 1, wc = w & 1;
  f32x4 acc[4][4];
#pragma unroll
  for (int a2 = 0; a2 < 4; ++a2)
#pragma unroll
    for (int b2 = 0; b2 < 4; ++b2) acc[a2][b2] = (f32x4){0.f, 0.f, 0.f, 0.f};

  // chunk ids u in [0,512): LDS offset u*16. plane = u>>8, row = (u>>1)&127,
  // half = u&1 -> global k-offset plane*32 + half*16. (two 32B-stride planes)
  const int u0 = (w * 2 + 0) * 64 + l;
  const int u1 = (w * 2 + 1) * 64 + l;
  const int row0 = (u0 >> 1) & 127, ko0 = ((u0 >> 8) << 5) + ((u0 & 1) << 4);
  const int row1 = (u1 >> 1) & 127, ko1 = ((u1 >> 8) << 5) + ((u1 & 1) << 4);
  char* lA0 = (char*)As + (w * 2 + 0) * 1024;  // wave-uniform base (+lane*16 by HW)
  char* lA1 = (char*)As + (w * 2 + 1) * 1024;
  char* lB0 = (char*)Bs + (w * 2 + 0) * 1024;
  char* lB1 = (char*)Bs + (w * 2 + 1) * 1024;

  for (int k0 = kbase; k0 < kbase + 4096; k0 += 64) {
    load_lds16(fb8 + (size_t)(rA + row0) * DF + k0 + ko0, lA0);
    load_lds16(fb8 + (size_t)(rA + row1) * DF + k0 + ko1, lA1);
    load_lds16(fb8 + (size_t)(rB + row0) * DF + k0 + ko0, lB0);
    load_lds16(fb8 + (size_t)(rB + row1) * DF + k0 + ko1, lB1);
    asm volatile("s_waitcnt vmcnt(0)" ::: "memory");
    __syncthreads();
#pragma unroll
    for (int s2 = 0; s2 < 2; ++s2) {           // plane s2: 32B-stride rows
      long long af[4], bv[4];
#pragma unroll
      for (int im = 0; im < 4; ++im)
        af[im] = *(const long long*)(As + s2 * 4096 + (wr * 64 + im * 16 + m) * 32 + q * 8);
#pragma unroll
      for (int in = 0; in < 4; ++in)
        bv[in] = *(const long long*)(Bs + s2 * 4096 + (wc * 64 + in * 16 + m) * 32 + q * 8);
#pragma unroll
      for (int im = 0; im < 4; ++im)
#pragma unroll
        for (int in = 0; in < 4; ++in)
          acc[im][in] = __builtin_amdgcn_mfma_f32_16x16x32_fp8_fp8(
              (long)af[im], (long)bv[in], acc[im][in], 0, 0, 0);
    }
    __syncthreads();
  }
#pragma unroll
  for (int im = 0; im < 4; ++im) {
    int row0w = rA + wr * 64 + im * 16 + q * 4;
#pragma unroll
    for (int in = 0; in < 4; ++in) {
      int col = rB + wc * 64 + in * 16 + m;
#pragma unroll
      for (int rg = 0; rg < 4; ++rg) {
        unsigned short h = f2bf(acc[im][in][rg]);
        Cd[(size_t)(row0w + rg) * N + col] = h;
        Cd[(size_t)col * N + row0w + rg] = h;   // symmetric image
      }
    }
  }
}

// ---------- 3. per-row top-20 (key = 2*(C0+C1) - sq_j, ties -> lower idx) ----------
__global__ void k_topk(const unsigned short* __restrict__ C0,
                       const unsigned short* __restrict__ C1,
                       const float* __restrict__ sq, unsigned* __restrict__ M) {
  int i = blockIdx.x * 4 + (threadIdx.x >> 6);
  int lane = threadIdx.x & 63;
  const unsigned short* r0 = C0 + (size_t)i * N;
  const unsigned short* r1 = C1 + (size_t)i * N;
  unsigned kk[40];
#pragma unroll
  for (int s = 0; s < 40; ++s) {
    int j = lane + (s << 6);
    float c = bf2f(r0[j]) + bf2f(r1[j]);
    kk[s] = sortkey(2.f * c - sq[j]);
  }
  unsigned long long removed = 0ull;
  unsigned myj = 0u;
  for (int t = 0; t < 20; ++t) {
    unsigned bk = 0u; int bs = -1;
#pragma unroll
    for (int s = 0; s < 40; ++s)
      if (!((removed >> s) & 1ull) && kk[s] > bk) { bk = kk[s]; bs = s; }
    unsigned long long packed = (bs < 0) ? 0ull
        : ((((unsigned long long)bk) << 32) |
           (unsigned long long)(0xFFFFFFFFu - (unsigned)(lane + (bs << 6))));
#pragma unroll
    for (int off2 = 32; off2 > 0; off2 >>= 1) {
      unsigned long long o = __shfl_xor(packed, off2, 64);
      if (o > packed) packed = o;
    }
    unsigned jw = 0xFFFFFFFFu - (unsigned)(packed & 0xFFFFFFFFull);
    if ((int)(jw & 63u) == lane) removed |= 1ull << (jw >> 6);
    if (t == lane) myj = jw;
  }
  if (lane < 20) atomicOr(&M[(size_t)i * 80 + (myj >> 5)], 1u << (myj & 31u));
}

// ---------- 4. symmetrize mask, build DENSE W row (bf16) + row sum D, dsi ----------
__global__ void k_csr(const unsigned short* __restrict__ C0,
                      const unsigned short* __restrict__ C1,
                      const float* __restrict__ sq,
                      const unsigned* __restrict__ M, unsigned short* __restrict__ Wd,
                      float* __restrict__ dsi) {
  int i = blockIdx.x, t = threadIdx.x;
  __shared__ unsigned Mrow[80];
  __shared__ float red[256];
  if (t < 80) Mrow[t] = M[(size_t)i * 80 + t];
  __syncthreads();
  const unsigned short* r0c = C0 + (size_t)i * N;
  const unsigned short* r1c = C1 + (size_t)i * N;
  float sqi = sq[i];
  int iw = i >> 5; unsigned ib = 1u << (i & 31);
  float dsum = 0.f;
#pragma unroll
  for (int s = 0; s < 10; ++s) {
    int j = t + (s << 8);
    unsigned mij = (Mrow[j >> 5] >> (j & 31)) & 1u;
    unsigned mji = M[(size_t)j * 80 + iw] & ib;
    unsigned short w = 0;
    if (mij | (mji != 0u)) {
      float c = bf2f(r0c[j]) + bf2f(r1c[j]);
      float wv = expf((2.f * c - sqi - sq[j]) * (1.f / 16384.f));
      w = f2bf(wv);
      dsum += wv;
    }
    Wd[(size_t)i * N + j] = w;
  }
  red[t] = dsum; __syncthreads();
  for (int o = 128; o > 0; o >>= 1) { if (t < o) red[t] += red[t + o]; __syncthreads(); }
  if (t == 0) dsi[i] = 1.f / sqrtf(red[0] + EPSF);
}

// ---------- 5. scale dense S in-place + init x,r for the row ----------
__global__ void k_scale_init(unsigned short* __restrict__ Wd, const float* __restrict__ dsi,
                             const int* __restrict__ slab, float* __restrict__ x,
                             float* __restrict__ r) {
  int i = blockIdx.x, t = threadIdx.x;
  __shared__ float ldsi[N];
  for (int s = t; s < N; s += 256) ldsi[s] = dsi[s];
  __syncthreads();
  float di = ldsi[i];
#pragma unroll
  for (int s = 0; s < 10; ++s) {
    int j = t + (s << 8);
    unsigned short w = Wd[(size_t)i * N + j];
    if (w) Wd[(size_t)i * N + j] = f2bf(bf2f(w) * di * ldsi[j]);
  }
  if (t < NCLS) {
    float y = 0.f;
    if (i < NSUP) y = (slab[i] == t) ? 1.f : 0.f;
    size_t o = (size_t)i * NCLS + t;
    x[o] = 0.f; r[o] = y;
  }
}

// ---------- 5b. init dT0 (class-major d, bf16): dT[c][i] = y ----------
__global__ void k_init_dT(const int* __restrict__ slab, unsigned short* __restrict__ dT0) {
  int c = blockIdx.x, t = threadIdx.x;
#pragma unroll
  for (int s = 0; s < 10; ++s) {
    int i = t + (s << 8);
    unsigned short v = 0;
    if (i < NSUP && slab[i] == c) v = 0x3F80u;  // bf16(1.0)
    dT0[(size_t)c * N + i] = v;
  }
}

// ---------- 6. one Chebyshev iteration via dense MFMA SpMV ----------
// 160 blocks x 256 thr. Block: rows [16b,16b+16). Wave w: classes [32w,32w+32)
// (two 16x16x32 bf16 MFMA frags). A = S row-major; B = dT class-major (both
// give contiguous 16B lane loads, same operand pattern as k_gemm). No LDS.
__global__ __launch_bounds__(256) void k_cheby(const unsigned short* __restrict__ Sd,
                        const float* __restrict__ rho_tab, const float* __restrict__ alpha,
                        float* __restrict__ x, float* __restrict__ r,
                        const unsigned short* __restrict__ dTc,
                        unsigned short* __restrict__ dTn, int it) {
  const int row0 = blockIdx.x * 16;
  const int w = threadIdx.x >> 6, l = threadIdx.x & 63;
  const int m = l & 15, kq = (l >> 4) << 3;
  const int n0 = w * 32;
  f32x4 acc0 = (f32x4){0.f, 0.f, 0.f, 0.f};
  f32x4 acc1 = (f32x4){0.f, 0.f, 0.f, 0.f};
  const unsigned short* Ap = Sd + (size_t)(row0 + m) * N + kq;
  const unsigned short* B0 = dTc + (size_t)(n0 + m) * N + kq;
  const unsigned short* B1 = dTc + (size_t)(n0 + 16 + m) * N + kq;
  for (int k = 0; k < N; k += 64) {      // 40 iters, 2 K-steps each
    bf16x8 a0 = *(const bf16x8*)(Ap + k);
    bf16x8 b00 = *(const bf16x8*)(B0 + k);
    bf16x8 b10 = *(const bf16x8*)(B1 + k);
    bf16x8 a1 = *(const bf16x8*)(Ap + k + 32);
    bf16x8 b01 = *(const bf16x8*)(B0 + k + 32);
    bf16x8 b11 = *(const bf16x8*)(B1 + k + 32);
    acc0 = __builtin_amdgcn_mfma_f32_16x16x32_bf16(a0, b00, acc0, 0, 0, 0);
    acc1 = __builtin_amdgcn_mfma_f32_16x16x32_bf16(a0, b10, acc1, 0, 0, 0);
    acc0 = __builtin_amdgcn_mfma_f32_16x16x32_bf16(a1, b01, acc0, 0, 0, 0);
    acc1 = __builtin_amdgcn_mfma_f32_16x16x32_bf16(a1, b11, acc1, 0, 0, 0);
  }
  const float ahat = alpha[0];
  const float rho = rho_tab[it], rhon = rho_tab[it + 1];
  const float cc1 = rhon * rho, cc2 = 2.f * rhon / ahat;
  const int q4 = (l >> 4) << 2;
#pragma unroll
  for (int f = 0; f < 2; ++f) {
    int c = n0 + f * 16 + m;
#pragma unroll
    for (int rg = 0; rg < 4; ++rg) {
      int i = row0 + q4 + rg;
      size_t o = (size_t)i * NCLS + c;
      float ax = f ? acc1[rg] : acc0[rg];
      float di = bf2f(dTc[(size_t)c * N + i]);
      x[o] += di;
      float rv = r[o] - (di - ahat * ax);
      r[o] = rv;
      dTn[(size_t)c * N + i] = f2bf(cc1 * di + cc2 * rv);
    }
  }
}

// ---------- 7. loss + acc ----------
__global__ void k_loss(const float* __restrict__ F, const int* __restrict__ slab,
                       const int* __restrict__ qlab, float* __restrict__ lossSum,
                       int* __restrict__ accCnt) {
  int i = blockIdx.x * 4 + (threadIdx.x >> 6);
  int lane = threadIdx.x & 63;
  int c0 = 2 * lane;
  float2 f = *(const float2*)(F + (size_t)i * NCLS + c0);
  float mx = fmaxf(f.x, f.y);
  for (int o2 = 32; o2 > 0; o2 >>= 1) mx = fmaxf(mx, __shfl_xor(mx, o2, 64));
  float se = expf(f.x - mx) + expf(f.y - mx);
  for (int o2 = 32; o2 > 0; o2 >>= 1) se += __shfl_xor(se, o2, 64);
  float lse = mx + logf(se);
  int gt = (i < NSUP) ? slab[i] : qlab[i - NSUP];
  float fg = ((c0 == gt) ? f.x : 0.f) + ((c0 + 1 == gt) ? f.y : 0.f);
  for (int o2 = 32; o2 > 0; o2 >>= 1) fg += __shfl_xor(fg, o2, 64);
  if (lane == 0) atomicAdd(lossSum, fg - lse);
  if (i >= NSUP) {
    float bvv; int bc;
    if (f.y > f.x) { bvv = f.y; bc = c0 + 1; } else { bvv = f.x; bc = c0; }
    unsigned long long packed =
        (((unsigned long long)sortkey(bvv)) << 32) | (unsigned long long)(unsigned)(127 - bc);
    for (int o2 = 32; o2 > 0; o2 >>= 1) {
      unsigned long long o = __shfl_xor(packed, o2, 64);
      if (o > packed) packed = o;
    }
    int cw = 127 - (int)(packed & 0xFFFFFFFFull);
    if (lane == 0 && cw == qlab[i - NSUP]) atomicAdd(accCnt, 1);
  }
}

// ---------- 8. finalize ----------
__global__ void k_final(const float* __restrict__ lossSum, const int* __restrict__ accCnt,
                        float* __restrict__ out) {
  out[0] = -lossSum[0] / (float)N;
  out[1] = (float)accCnt[0] / (float)NQ;
}

// ---------- launch ----------
extern "C" void kernel_launch(void* const* d_in, const int* in_sizes, int n_in,
                              void* d_out, int out_size, void* d_ws, size_t ws_size,
                              hipStream_t stream) {
  const float* feats = (const float*)d_in[0];
  const float* alpha = (const float*)d_in[1];
  const int* slab = (const int*)d_in[2];
  const int* qlab = (const int*)d_in[3];
  float* out = (float*)d_out;
  char* ws = (char*)d_ws;

  // ws layout (bytes). C0/C1 (bf16, 13,107,200 each) die after k_csr; x/r/dT
  // overlay that region. Dense S (13,107,200) overlays the dead fb8 region.
  unsigned short* C0 = (unsigned short*)(ws + 0);
  unsigned short* C1 = (unsigned short*)(ws + 13107200);
  float* x           = (float*)(ws + 0);
  float* r           = (float*)(ws + 1310720);
  unsigned short* dT0 = (unsigned short*)(ws + 2621440);  // bf16 class-major, 655,360 B
  unsigned short* dT1 = (unsigned short*)(ws + 3276800);
  unsigned* M   = (unsigned*)(ws + 26214400);          // 819,200 B bitmask
  float* ctrl   = (float*)(ws + 27033600);             // lossSum, accCnt, rho_tab
  float* lossSum = ctrl;
  int* accCnt   = (int*)(ctrl + 1);
  float* rho_tab = ctrl + 4;                           // 128 floats
  float* sq     = (float*)(ws + 27034624);
  float* dsi    = (float*)(ws + 27044864);
  unsigned char* fb8 = (unsigned char*)(ws + 27065344);     // 20,971,520 B fp8 feats
  unsigned short* Sd = (unsigned short*)(ws + 27065344);    // dense bf16 S, overlays fb8
  // total ws required: 40,172,544 bytes

  hipMemsetAsync(ws + 26214400, 0, 820224, stream);    // M + ctrl
  k_prep<<<N, 256, 0, stream>>>(feats, fb8, sq, alpha, rho_tab);
  k_gemm<<<420, 256, 0, stream>>>(fb8, C0, C1);        // lower-tri tiles, split-K x2
  k_topk<<<N / 4, 256, 0, stream>>>(C0, C1, sq, M);
  k_csr<<<N, 256, 0, stream>>>(C0, C1, sq, M, Sd, dsi);
  k_scale_init<<<N, 256, 0, stream>>>(Sd, dsi, slab, x, r);
  k_init_dT<<<NCLS, 256, 0, stream>>>(slab, dT0);
  for (int it = 0; it < TITER; ++it) {
    const unsigned short* dc = (it & 1) ? dT1 : dT0;
    unsigned short* dn = (it & 1) ? dT0 : dT1;
    k_cheby<<<N / 16, 256, 0, stream>>>(Sd, rho_tab, alpha, x, r, dc, dn, it);
  }
  k_loss<<<N / 4, 256, 0, stream>>>(x, slab, qlab, lossSum, accCnt);
  k_final<<<1, 1, 0, stream>>>(lossSum, accCnt, out);
}

// Round 10
// 448.053 us; speedup vs baseline: 1.9139x; 1.9139x over previous
//
#include <hip/hip_runtime.h>
#include <hip/hip_fp8.h>
#include <stdint.h>

#define N 2560
#define NSUP 640
#define NQ 1920
#define NCLS 128
#define DF 8192
#define CAP 1024
#define TITER 12
#define EPSF 2.220446049250313e-16f

typedef __attribute__((ext_vector_type(4))) float f32x4;

// ---------- helpers ----------
__device__ __forceinline__ unsigned short f2bf(float f) {
  unsigned u = __float_as_uint(f);
  return (unsigned short)((u + 0x7FFFu + ((u >> 16) & 1u)) >> 16);  // RNE
}
__device__ __forceinline__ float bf2f(unsigned short h) {
  return __uint_as_float(((unsigned)h) << 16);
}
__device__ __forceinline__ unsigned char f2e4m3(float f) {
  __hip_fp8_e4m3 h(f);                 // OCP e4m3fn on gfx950
  return (unsigned char)h.__x;
}
__device__ __forceinline__ unsigned sortkey(float f) {
  unsigned u = __float_as_uint(f);
  return (u & 0x80000000u) ? ~u : (u | 0x80000000u);
}
__device__ __forceinline__ void load_lds16(const void* g, void* l) {
  __builtin_amdgcn_global_load_lds((const __attribute__((address_space(1))) void*)g,
                                   (__attribute__((address_space(3))) void*)l, 16, 0, 0);
}

// ---------- 1. fp32 -> fp8 copy + row sumsq + rho table ----------
__global__ void k_prep(const float* __restrict__ feats, unsigned char* __restrict__ fb8,
                       float* __restrict__ sq, const float* __restrict__ alpha,
                       float* __restrict__ rho_tab) {
  int i = blockIdx.x, t = threadIdx.x;
  const float4* src = (const float4*)(feats + (size_t)i * DF);
  uchar4* dst = (uchar4*)(fb8 + (size_t)i * DF);
  float s = 0.f;
#pragma unroll
  for (int it = 0; it < 8; ++it) {
    float4 v = src[it * 256 + t];
    s = fmaf(v.x, v.x, s); s = fmaf(v.y, v.y, s);
    s = fmaf(v.z, v.z, s); s = fmaf(v.w, v.w, s);
    uchar4 o; o.x = f2e4m3(v.x); o.y = f2e4m3(v.y); o.z = f2e4m3(v.z); o.w = f2e4m3(v.w);
    dst[it * 256 + t] = o;
  }
  __shared__ float red[256];
  red[t] = s; __syncthreads();
  for (int o = 128; o > 0; o >>= 1) { if (t < o) red[t] += red[t + o]; __syncthreads(); }
  if (t == 0) sq[i] = red[0];
  if (i == 0 && t == 0) {  // Chebyshev rho recurrence (theta=1, delta=alpha)
    float a = alpha[0];
    float rho = a; rho_tab[0] = rho;
    for (int k2 = 1; k2 < 128; ++k2) { rho = 1.f / (2.f / a - rho); rho_tab[k2] = rho; }
  }
}

// ---------- 2. C = fb8 @ fb8^T (fp8 MFMA), sym-half + split-K x3, bf16 out ----------
// 630 blocks: ks = bid/210 -> K [ks*2752, +2752/2752/2688) into C0/C1/C2.
// LDS tile: two 32B-stride planes (round-8 bank-conflict fix).
__global__ __launch_bounds__(256, 2) void k_gemm(const unsigned char* __restrict__ fb8,
                                                 unsigned short* __restrict__ C0,
                                                 unsigned short* __restrict__ C1,
                                                 unsigned short* __restrict__ C2) {
  __shared__ __align__(16) unsigned char As[128 * 64];
  __shared__ __align__(16) unsigned char Bs[128 * 64];
  int bid = blockIdx.x;
  int ks = (bid >= 210) + (bid >= 420);
  int tid2 = bid - 210 * ks;
  unsigned short* Cd = (ks == 0) ? C0 : (ks == 1 ? C1 : C2);
  const int kbase = ks * 2752;
  const int kend = kbase + (ks < 2 ? 2752 : 2688);
  int bx = (int)((sqrtf(8.0f * (float)tid2 + 1.0f) - 1.0f) * 0.5f);
  while ((bx + 1) * (bx + 2) / 2 <= tid2) ++bx;
  while (bx * (bx + 1) / 2 > tid2) --bx;
  int by = tid2 - bx * (bx + 1) / 2;           // by <= bx
  const int rA = by * 128, rB = bx * 128;
  const int t = threadIdx.x, w = t >> 6, l = t & 63;
  const int q = l >> 4, m = l & 15;
  const int wr = w >> 1, wc = w & 1;
  f32x4 acc[4][4];
#pragma unroll
  for (int a2 = 0; a2 < 4; ++a2)
#pragma unroll
    for (int b2 = 0; b2 < 4; ++b2) acc[a2][b2] = (f32x4){0.f, 0.f, 0.f, 0.f};

  // chunk ids u in [0,512): LDS offset u*16. plane = u>>8, row = (u>>1)&127,
  // half = u&1 -> global k-offset plane*32 + half*16. (two 32B-stride planes)
  const int u0 = (w * 2 + 0) * 64 + l;
  const int u1 = (w * 2 + 1) * 64 + l;
  const int row0 = (u0 >> 1) & 127, ko0 = ((u0 >> 8) << 5) + ((u0 & 1) << 4);
  const int row1 = (u1 >> 1) & 127, ko1 = ((u1 >> 8) << 5) + ((u1 & 1) << 4);
  char* lA0 = (char*)As + (w * 2 + 0) * 1024;  // wave-uniform base (+lane*16 by HW)
  char* lA1 = (char*)As + (w * 2 + 1) * 1024;
  char* lB0 = (char*)Bs + (w * 2 + 0) * 1024;
  char* lB1 = (char*)Bs + (w * 2 + 1) * 1024;

  for (int k0 = kbase; k0 < kend; k0 += 64) {
    load_lds16(fb8 + (size_t)(rA + row0) * DF + k0 + ko0, lA0);
    load_lds16(fb8 + (size_t)(rA + row1) * DF + k0 + ko1, lA1);
    load_lds16(fb8 + (size_t)(rB + row0) * DF + k0 + ko0, lB0);
    load_lds16(fb8 + (size_t)(rB + row1) * DF + k0 + ko1, lB1);
    asm volatile("s_waitcnt vmcnt(0)" ::: "memory");
    __syncthreads();
#pragma unroll
    for (int s2 = 0; s2 < 2; ++s2) {           // plane s2: 32B-stride rows
      long long af[4], bv[4];
#pragma unroll
      for (int im = 0; im < 4; ++im)
        af[im] = *(const long long*)(As + s2 * 4096 + (wr * 64 + im * 16 + m) * 32 + q * 8);
#pragma unroll
      for (int in = 0; in < 4; ++in)
        bv[in] = *(const long long*)(Bs + s2 * 4096 + (wc * 64 + in * 16 + m) * 32 + q * 8);
#pragma unroll
      for (int im = 0; im < 4; ++im)
#pragma unroll
        for (int in = 0; in < 4; ++in)
          acc[im][in] = __builtin_amdgcn_mfma_f32_16x16x32_fp8_fp8(
              (long)af[im], (long)bv[in], acc[im][in], 0, 0, 0);
    }
    __syncthreads();
  }
#pragma unroll
  for (int im = 0; im < 4; ++im) {
    int row0w = rA + wr * 64 + im * 16 + q * 4;
#pragma unroll
    for (int in = 0; in < 4; ++in) {
      int col = rB + wc * 64 + in * 16 + m;
#pragma unroll
      for (int rg = 0; rg < 4; ++rg) {
        unsigned short h = f2bf(acc[im][in][rg]);
        Cd[(size_t)(row0w + rg) * N + col] = h;
        Cd[(size_t)col * N + row0w + rg] = h;   // symmetric image
      }
    }
  }
}

// ---------- 3. per-row top-20 (key = 2*(C0+C1+C2) - sq_j, ties -> lower idx) ----------
__global__ void k_topk(const unsigned short* __restrict__ C0,
                       const unsigned short* __restrict__ C1,
                       const unsigned short* __restrict__ C2,
                       const float* __restrict__ sq, unsigned* __restrict__ M) {
  int i = blockIdx.x * 4 + (threadIdx.x >> 6);
  int lane = threadIdx.x & 63;
  const unsigned short* r0 = C0 + (size_t)i * N;
  const unsigned short* r1 = C1 + (size_t)i * N;
  const unsigned short* r2 = C2 + (size_t)i * N;
  unsigned kk[40];
#pragma unroll
  for (int s = 0; s < 40; ++s) {
    int j = lane + (s << 6);
    float c = bf2f(r0[j]) + bf2f(r1[j]) + bf2f(r2[j]);
    kk[s] = sortkey(2.f * c - sq[j]);
  }
  unsigned long long removed = 0ull;
  unsigned myj = 0u;
  for (int t = 0; t < 20; ++t) {
    unsigned bk = 0u; int bs = -1;
#pragma unroll
    for (int s = 0; s < 40; ++s)
      if (!((removed >> s) & 1ull) && kk[s] > bk) { bk = kk[s]; bs = s; }
    unsigned long long packed = (bs < 0) ? 0ull
        : ((((unsigned long long)bk) << 32) |
           (unsigned long long)(0xFFFFFFFFu - (unsigned)(lane + (bs << 6))));
#pragma unroll
    for (int off2 = 32; off2 > 0; off2 >>= 1) {
      unsigned long long o = __shfl_xor(packed, off2, 64);
      if (o > packed) packed = o;
    }
    unsigned jw = 0xFFFFFFFFu - (unsigned)(packed & 0xFFFFFFFFull);
    if ((int)(jw & 63u) == lane) removed |= 1ull << (jw >> 6);
    if (t == lane) myj = jw;
  }
  if (lane < 20) atomicOr(&M[(size_t)i * 80 + (myj >> 5)], 1u << (myj & 31u));
}

// ---------- 4. symmetrize mask, build packed CSR (u16 col | bf16 W), D, dsi ----------
__global__ void k_csr(const unsigned short* __restrict__ C0,
                      const unsigned short* __restrict__ C1,
                      const unsigned short* __restrict__ C2,
                      const float* __restrict__ sq,
                      const unsigned* __restrict__ M, unsigned* __restrict__ csrG,
                      int* __restrict__ degG, float* __restrict__ dsi) {
  int i = blockIdx.x, t = threadIdx.x;
  __shared__ unsigned Mrow[80];
  __shared__ int degs;
  __shared__ unsigned packs[CAP];
  __shared__ float red[256];
  if (t < 80) Mrow[t] = M[(size_t)i * 80 + t];
  if (t == 0) degs = 0;
  __syncthreads();
  const unsigned short* r0c = C0 + (size_t)i * N;
  const unsigned short* r1c = C1 + (size_t)i * N;
  const unsigned short* r2c = C2 + (size_t)i * N;
  float sqi = sq[i];
  int iw = i >> 5; unsigned ib = 1u << (i & 31);
  float dsum = 0.f;
#pragma unroll
  for (int s = 0; s < 10; ++s) {
    int j = t + (s << 8);
    unsigned mij = (Mrow[j >> 5] >> (j & 31)) & 1u;
    unsigned mji = M[(size_t)j * 80 + iw] & ib;
    if (mij | (mji != 0u)) {
      float c = bf2f(r0c[j]) + bf2f(r1c[j]) + bf2f(r2c[j]);
      float wv = expf((2.f * c - sqi - sq[j]) * (1.f / 16384.f));
      int sl = atomicAdd(&degs, 1);
      if (sl < CAP) packs[sl] = (((unsigned)f2bf(wv)) << 16) | (unsigned)j;
      dsum += wv;
    }
  }
  red[t] = dsum; __syncthreads();
  for (int o = 128; o > 0; o >>= 1) { if (t < o) red[t] += red[t + o]; __syncthreads(); }
  if (t == 0) {
    degG[i] = degs > CAP ? CAP : degs;
    dsi[i] = 1.f / sqrtf(red[0] + EPSF);
  }
  __syncthreads();
  int dgc = degs > CAP ? CAP : degs;
  for (int sl = t; sl < dgc; sl += 256)
    csrG[(size_t)i * CAP + sl] = packs[sl];
}

// ---------- 5. merged: S edge scaling (in packed CSR) + Chebyshev init ----------
__global__ void k_scale_init(unsigned* __restrict__ csrG, const int* __restrict__ degG,
                             const float* __restrict__ dsi, const int* __restrict__ slab,
                             float* __restrict__ x, float* __restrict__ r,
                             unsigned short* __restrict__ d0) {
  int i = blockIdx.x * 4 + (threadIdx.x >> 6);
  int lane = threadIdx.x & 63;
  float di = dsi[i];
  int dg = degG[i];
  for (int s = lane; s < dg; s += 64) {
    unsigned p = csrG[(size_t)i * CAP + s];
    int j = p & 0xFFFFu;
    float wv = __uint_as_float(p & 0xFFFF0000u);
    wv *= di * dsi[j];
    csrG[(size_t)i * CAP + s] = (((unsigned)f2bf(wv)) << 16) | (unsigned)j;
  }
  int c0 = 2 * lane;
  float y0 = 0.f, y1 = 0.f;
  if (i < NSUP) {
    int lbl = slab[i];
    y0 = (lbl == c0) ? 1.f : 0.f;
    y1 = (lbl == c0 + 1) ? 1.f : 0.f;
  }
  size_t o = (size_t)i * NCLS + c0;
  x[o] = 0.f; x[o + 1] = 0.f;
  r[o] = y0;  r[o + 1] = y1;
  ushort2 dini; dini.x = f2bf(y0); dini.y = f2bf(y1);
  *(ushort2*)(d0 + o) = dini;
}

// ---------- 6. one Chebyshev iteration (A = I - alpha*S), d in bf16 ----------
// Champion structure (round 6/7, 16.2 us/iter): block per row, 256 threads,
// g = t&31 (4 classes), p = t>>5 (8 edge partitions), 8-deep unrolled gather.
__global__ __launch_bounds__(256) void k_cheby(const unsigned* __restrict__ csrG,
                        const int* __restrict__ degG, const float* __restrict__ rho_tab,
                        const float* __restrict__ alpha, float* __restrict__ x,
                        float* __restrict__ r, const unsigned short* __restrict__ dcur,
                        unsigned short* __restrict__ dnxt, int it) {
  int i = blockIdx.x;
  int t = threadIdx.x;
  int g4 = (t & 31) << 2, p = t >> 5;
  __shared__ unsigned lcv[CAP];
  __shared__ float4 partial[256];
  int dg = degG[i];
  for (int s = t; s < dg; s += 256) lcv[s] = csrG[(size_t)i * CAP + s];
  __syncthreads();
  float4 acc = make_float4(0.f, 0.f, 0.f, 0.f);
  int s = p;
  for (; s + 56 < dg; s += 64) {         // 8 partitions x 8-deep unroll
    unsigned uu[8]; ushort4 a[8];
#pragma unroll
    for (int u = 0; u < 8; ++u) {
      uu[u] = lcv[s + 8 * u];
      a[u] = *(const ushort4*)(dcur + (size_t)(uu[u] & 0xFFFFu) * NCLS + g4);
    }
#pragma unroll
    for (int u = 0; u < 8; ++u) {
      float v = __uint_as_float(uu[u] & 0xFFFF0000u);
      acc.x = fmaf(v, bf2f(a[u].x), acc.x);
      acc.y = fmaf(v, bf2f(a[u].y), acc.y);
      acc.z = fmaf(v, bf2f(a[u].z), acc.z);
      acc.w = fmaf(v, bf2f(a[u].w), acc.w);
    }
  }
  for (; s < dg; s += 8) {               // tail
    unsigned uu = lcv[s];
    ushort4 a = *(const ushort4*)(dcur + (size_t)(uu & 0xFFFFu) * NCLS + g4);
    float v = __uint_as_float(uu & 0xFFFF0000u);
    acc.x = fmaf(v, bf2f(a.x), acc.x); acc.y = fmaf(v, bf2f(a.y), acc.y);
    acc.z = fmaf(v, bf2f(a.z), acc.z); acc.w = fmaf(v, bf2f(a.w), acc.w);
  }
  partial[t] = acc;
  __syncthreads();
  for (int off = 128; off >= 32; off >>= 1) {
    if (t < off) {
      float4 o = partial[t + off];
      float4 m = partial[t];
      m.x += o.x; m.y += o.y; m.z += o.z; m.w += o.w;
      partial[t] = m;
    }
    __syncthreads();
  }
  if (t < 32) {                          // classes 4t..4t+3
    float4 ax = partial[t];
    float ahat = alpha[0];
    float rho = rho_tab[it], rhon = rho_tab[it + 1];
    float cc1 = rhon * rho, cc2 = 2.f * rhon / ahat;
    size_t o = (size_t)i * NCLS + 4 * t;
    ushort4 dv = *(const ushort4*)(dcur + o);
    float4 di; di.x = bf2f(dv.x); di.y = bf2f(dv.y); di.z = bf2f(dv.z); di.w = bf2f(dv.w);
    float4 xv = *(float4*)(x + o);
    float4 rv = *(float4*)(r + o);
    float4 q;
    q.x = di.x - ahat * ax.x; q.y = di.y - ahat * ax.y;
    q.z = di.z - ahat * ax.z; q.w = di.w - ahat * ax.w;
    xv.x += di.x; xv.y += di.y; xv.z += di.z; xv.w += di.w;
    rv.x -= q.x; rv.y -= q.y; rv.z -= q.z; rv.w -= q.w;
    ushort4 dn;
    dn.x = f2bf(cc1 * di.x + cc2 * rv.x); dn.y = f2bf(cc1 * di.y + cc2 * rv.y);
    dn.z = f2bf(cc1 * di.z + cc2 * rv.z); dn.w = f2bf(cc1 * di.w + cc2 * rv.w);
    *(float4*)(x + o) = xv;
    *(float4*)(r + o) = rv;
    *(ushort4*)(dnxt + o) = dn;
  }
}

// ---------- 7. loss + acc ----------
__global__ void k_loss(const float* __restrict__ F, const int* __restrict__ slab,
                       const int* __restrict__ qlab, float* __restrict__ lossSum,
                       int* __restrict__ accCnt) {
  int i = blockIdx.x * 4 + (threadIdx.x >> 6);
  int lane = threadIdx.x & 63;
  int c0 = 2 * lane;
  float2 f = *(const float2*)(F + (size_t)i * NCLS + c0);
  float mx = fmaxf(f.x, f.y);
  for (int o2 = 32; o2 > 0; o2 >>= 1) mx = fmaxf(mx, __shfl_xor(mx, o2, 64));
  float se = expf(f.x - mx) + expf(f.y - mx);
  for (int o2 = 32; o2 > 0; o2 >>= 1) se += __shfl_xor(se, o2, 64);
  float lse = mx + logf(se);
  int gt = (i < NSUP) ? slab[i] : qlab[i - NSUP];
  float fg = ((c0 == gt) ? f.x : 0.f) + ((c0 + 1 == gt) ? f.y : 0.f);
  for (int o2 = 32; o2 > 0; o2 >>= 1) fg += __shfl_xor(fg, o2, 64);
  if (lane == 0) atomicAdd(lossSum, fg - lse);
  if (i >= NSUP) {
    float bvv; int bc;
    if (f.y > f.x) { bvv = f.y; bc = c0 + 1; } else { bvv = f.x; bc = c0; }
    unsigned long long packed =
        (((unsigned long long)sortkey(bvv)) << 32) | (unsigned long long)(unsigned)(127 - bc);
    for (int o2 = 32; o2 > 0; o2 >>= 1) {
      unsigned long long o = __shfl_xor(packed, o2, 64);
      if (o > packed) packed = o;
    }
    int cw = 127 - (int)(packed & 0xFFFFFFFFull);
    if (lane == 0 && cw == qlab[i - NSUP]) atomicAdd(accCnt, 1);
  }
}

// ---------- 8. finalize ----------
__global__ void k_final(const float* __restrict__ lossSum, const int* __restrict__ accCnt,
                        float* __restrict__ out) {
  out[0] = -lossSum[0] / (float)N;
  out[1] = (float)accCnt[0] / (float)NQ;
}

// ---------- launch ----------
extern "C" void kernel_launch(void* const* d_in, const int* in_sizes, int n_in,
                              void* d_out, int out_size, void* d_ws, size_t ws_size,
                              hipStream_t stream) {
  const float* feats = (const float*)d_in[0];
  const float* alpha = (const float*)d_in[1];
  const int* slab = (const int*)d_in[2];
  const int* qlab = (const int*)d_in[3];
  float* out = (float*)d_out;
  char* ws = (char*)d_ws;

  // ws layout (bytes). C0/C1/C2 (bf16, 13,107,200 each) die after k_csr;
  // x/r/d0/d1 overlay C0. csrG overlays fb8 after k_gemm.
  unsigned short* C0 = (unsigned short*)(ws + 0);
  unsigned short* C1 = (unsigned short*)(ws + 13107200);
  unsigned short* C2 = (unsigned short*)(ws + 26214400);
  float* x           = (float*)(ws + 0);
  float* r           = (float*)(ws + 1310720);
  unsigned short* d0 = (unsigned short*)(ws + 2621440);   // bf16, 655,360 B
  unsigned short* d1 = (unsigned short*)(ws + 3276800);   // bf16, 655,360 B
  unsigned* M   = (unsigned*)(ws + 39321600);          // 819,200 B bitmask
  float* ctrl   = (float*)(ws + 40140800);             // lossSum, accCnt, rho_tab
  float* lossSum = ctrl;
  int* accCnt   = (int*)(ctrl + 1);
  float* rho_tab = ctrl + 4;                           // 128 floats
  float* sq     = (float*)(ws + 40141824);
  float* dsi    = (float*)(ws + 40152064);
  int* degG     = (int*)(ws + 40162304);
  unsigned char* fb8 = (unsigned char*)(ws + 40172544);   // 20,971,520 B fp8 feats
  unsigned* csrG = (unsigned*)(ws + 40172544);            // overlays fb8 after GEMM
  // total ws required: 61,144,064 bytes

  hipMemsetAsync(ws + 39321600, 0, 820224, stream);    // M + ctrl
  k_prep<<<N, 256, 0, stream>>>(feats, fb8, sq, alpha, rho_tab);
  k_gemm<<<630, 256, 0, stream>>>(fb8, C0, C1, C2);    // lower-tri tiles, split-K x3
  k_topk<<<N / 4, 256, 0, stream>>>(C0, C1, C2, sq, M);
  k_csr<<<N, 256, 0, stream>>>(C0, C1, C2, sq, M, csrG, degG, dsi);
  k_scale_init<<<N / 4, 256, 0, stream>>>(csrG, degG, dsi, slab, x, r, d0);
  for (int it = 0; it < TITER; ++it) {
    const unsigned short* dc = (it & 1) ? d1 : d0;
    unsigned short* dn = (it & 1) ? d0 : d1;
    k_cheby<<<N, 256, 0, stream>>>(csrG, degG, rho_tab, alpha, x, r, dc, dn, it);
  }
  k_loss<<<N / 4, 256, 0, stream>>>(x, slab, qlab, lossSum, accCnt);
  k_final<<<1, 1, 0, stream>>>(lossSum, accCnt, out);
}

// Round 11
// 399.775 us; speedup vs baseline: 2.1450x; 1.1208x over previous
//
#include <hip/hip_runtime.h>
#include <hip/hip_fp8.h>
#include <stdint.h>

#define N 2560
#define NSUP 640
#define NQ 1920
#define NCLS 128
#define DF 8192
#define CAP 1024
#define TITER 8
#define EPSF 2.220446049250313e-16f

typedef __attribute__((ext_vector_type(4))) float f32x4;

// ---------- helpers ----------
__device__ __forceinline__ unsigned short f2bf(float f) {
  unsigned u = __float_as_uint(f);
  return (unsigned short)((u + 0x7FFFu + ((u >> 16) & 1u)) >> 16);  // RNE
}
__device__ __forceinline__ float bf2f(unsigned short h) {
  return __uint_as_float(((unsigned)h) << 16);
}
__device__ __forceinline__ unsigned char f2e4m3(float f) {
  __hip_fp8_e4m3 h(f);                 // OCP e4m3fn on gfx950
  return (unsigned char)h.__x;
}
__device__ __forceinline__ unsigned sortkey(float f) {
  unsigned u = __float_as_uint(f);
  return (u & 0x80000000u) ? ~u : (u | 0x80000000u);
}
__device__ __forceinline__ void load_lds16(const void* g, void* l) {
  __builtin_amdgcn_global_load_lds((const __attribute__((address_space(1))) void*)g,
                                   (__attribute__((address_space(3))) void*)l, 16, 0, 0);
}

// ---------- 1. fp32 -> fp8 copy + row sumsq + rho table ----------
__global__ void k_prep(const float* __restrict__ feats, unsigned char* __restrict__ fb8,
                       float* __restrict__ sq, const float* __restrict__ alpha,
                       float* __restrict__ rho_tab) {
  int i = blockIdx.x, t = threadIdx.x;
  const float4* src = (const float4*)(feats + (size_t)i * DF);
  uchar4* dst = (uchar4*)(fb8 + (size_t)i * DF);
  float s = 0.f;
#pragma unroll
  for (int it = 0; it < 8; ++it) {
    float4 v = src[it * 256 + t];
    s = fmaf(v.x, v.x, s); s = fmaf(v.y, v.y, s);
    s = fmaf(v.z, v.z, s); s = fmaf(v.w, v.w, s);
    uchar4 o; o.x = f2e4m3(v.x); o.y = f2e4m3(v.y); o.z = f2e4m3(v.z); o.w = f2e4m3(v.w);
    dst[it * 256 + t] = o;
  }
  __shared__ float red[256];
  red[t] = s; __syncthreads();
  for (int o = 128; o > 0; o >>= 1) { if (t < o) red[t] += red[t + o]; __syncthreads(); }
  if (t == 0) sq[i] = red[0];
  if (i == 0 && t == 0) {  // Chebyshev rho recurrence (theta=1, delta=alpha)
    float a = alpha[0];
    float rho = a; rho_tab[0] = rho;
    for (int k2 = 1; k2 < 128; ++k2) { rho = 1.f / (2.f / a - rho); rho_tab[k2] = rho; }
  }
}

// ---------- 2. C = fb8 @ fb8^T (fp8 MFMA), sym-half + split-K x3, bf16 out ----------
// 630 blocks: ks = bid/210 -> K [ks*2752, +2752/2752/2688) into C0/C1/C2.
// LDS tile: two 32B-stride planes; the two 16B half-chunks of each row's 32B
// K-slice are XOR-swizzled by bit (row>>2)&1 so fragment b64 reads spread
// 2 lanes/bank (free) instead of 4-way (round-10: 2.06e7 conflicts).
__global__ __launch_bounds__(256, 2) void k_gemm(const unsigned char* __restrict__ fb8,
                                                 unsigned short* __restrict__ C0,
                                                 unsigned short* __restrict__ C1,
                                                 unsigned short* __restrict__ C2) {
  __shared__ __align__(16) unsigned char As[128 * 64];
  __shared__ __align__(16) unsigned char Bs[128 * 64];
  int bid = blockIdx.x;
  int ks = (bid >= 210) + (bid >= 420);
  int tid2 = bid - 210 * ks;
  unsigned short* Cd = (ks == 0) ? C0 : (ks == 1 ? C1 : C2);
  const int kbase = ks * 2752;
  const int kend = kbase + (ks < 2 ? 2752 : 2688);
  int bx = (int)((sqrtf(8.0f * (float)tid2 + 1.0f) - 1.0f) * 0.5f);
  while ((bx + 1) * (bx + 2) / 2 <= tid2) ++bx;
  while (bx * (bx + 1) / 2 > tid2) --bx;
  int by = tid2 - bx * (bx + 1) / 2;           // by <= bx
  const int rA = by * 128, rB = bx * 128;
  const int t = threadIdx.x, w = t >> 6, l = t & 63;
  const int q = l >> 4, m = l & 15;
  const int wr = w >> 1, wc = w & 1;
  f32x4 acc[4][4];
#pragma unroll
  for (int a2 = 0; a2 < 4; ++a2)
#pragma unroll
    for (int b2 = 0; b2 < 4; ++b2) acc[a2][b2] = (f32x4){0.f, 0.f, 0.f, 0.f};

  // staging chunk u in [0,512): LDS offset u*16. plane=u>>8, row=(u>>1)&127,
  // slot-half=u&1 holds global half (u&1)^((u>>3)&1) -> k-off plane*32+half*16.
  const int u0 = (w * 2 + 0) * 64 + l;
  const int u1 = (w * 2 + 1) * 64 + l;
  const int row0 = (u0 >> 1) & 127;
  const int ko0 = ((u0 >> 8) << 5) + ((((u0 & 1) ^ ((u0 >> 3) & 1))) << 4);
  const int row1 = (u1 >> 1) & 127;
  const int ko1 = ((u1 >> 8) << 5) + ((((u1 & 1) ^ ((u1 >> 3) & 1))) << 4);
  char* lA0 = (char*)As + (w * 2 + 0) * 1024;  // wave-uniform base (+lane*16 by HW)
  char* lA1 = (char*)As + (w * 2 + 1) * 1024;
  char* lB0 = (char*)Bs + (w * 2 + 0) * 1024;
  char* lB1 = (char*)Bs + (w * 2 + 1) * 1024;
  // fragment read swizzle: lane-constant half-select (q>>1) ^ ((m>>2)&1)
  const int qoff = ((((q >> 1) ^ ((m >> 2) & 1))) << 4) + ((q & 1) << 3);

  for (int k0 = kbase; k0 < kend; k0 += 64) {
    load_lds16(fb8 + (size_t)(rA + row0) * DF + k0 + ko0, lA0);
    load_lds16(fb8 + (size_t)(rA + row1) * DF + k0 + ko1, lA1);
    load_lds16(fb8 + (size_t)(rB + row0) * DF + k0 + ko0, lB0);
    load_lds16(fb8 + (size_t)(rB + row1) * DF + k0 + ko1, lB1);
    asm volatile("s_waitcnt vmcnt(0)" ::: "memory");
    __syncthreads();
#pragma unroll
    for (int s2 = 0; s2 < 2; ++s2) {           // plane s2: 32B-stride rows
      long long af[4], bv[4];
#pragma unroll
      for (int im = 0; im < 4; ++im)
        af[im] = *(const long long*)(As + s2 * 4096 + (wr * 64 + im * 16 + m) * 32 + qoff);
#pragma unroll
      for (int in = 0; in < 4; ++in)
        bv[in] = *(const long long*)(Bs + s2 * 4096 + (wc * 64 + in * 16 + m) * 32 + qoff);
#pragma unroll
      for (int im = 0; im < 4; ++im)
#pragma unroll
        for (int in = 0; in < 4; ++in)
          acc[im][in] = __builtin_amdgcn_mfma_f32_16x16x32_fp8_fp8(
              (long)af[im], (long)bv[in], acc[im][in], 0, 0, 0);
    }
    __syncthreads();
  }
#pragma unroll
  for (int im = 0; im < 4; ++im) {
    int row0w = rA + wr * 64 + im * 16 + q * 4;
#pragma unroll
    for (int in = 0; in < 4; ++in) {
      int col = rB + wc * 64 + in * 16 + m;
#pragma unroll
      for (int rg = 0; rg < 4; ++rg) {
        unsigned short h = f2bf(acc[im][in][rg]);
        Cd[(size_t)(row0w + rg) * N + col] = h;
        Cd[(size_t)col * N + row0w + rg] = h;   // symmetric image
      }
    }
  }
}

// ---------- 3. per-row top-20 (key = 2*(C0+C1+C2) - sq_j, ties -> lower idx) ----------
__global__ void k_topk(const unsigned short* __restrict__ C0,
                       const unsigned short* __restrict__ C1,
                       const unsigned short* __restrict__ C2,
                       const float* __restrict__ sq, unsigned* __restrict__ M) {
  int i = blockIdx.x * 4 + (threadIdx.x >> 6);
  int lane = threadIdx.x & 63;
  const unsigned short* r0 = C0 + (size_t)i * N;
  const unsigned short* r1 = C1 + (size_t)i * N;
  const unsigned short* r2 = C2 + (size_t)i * N;
  unsigned kk[40];
#pragma unroll
  for (int s = 0; s < 40; ++s) {
    int j = lane + (s << 6);
    float c = bf2f(r0[j]) + bf2f(r1[j]) + bf2f(r2[j]);
    kk[s] = sortkey(2.f * c - sq[j]);
  }
  unsigned long long removed = 0ull;
  unsigned myj = 0u;
  for (int t = 0; t < 20; ++t) {
    unsigned bk = 0u; int bs = -1;
#pragma unroll
    for (int s = 0; s < 40; ++s)
      if (!((removed >> s) & 1ull) && kk[s] > bk) { bk = kk[s]; bs = s; }
    unsigned long long packed = (bs < 0) ? 0ull
        : ((((unsigned long long)bk) << 32) |
           (unsigned long long)(0xFFFFFFFFu - (unsigned)(lane + (bs << 6))));
#pragma unroll
    for (int off2 = 32; off2 > 0; off2 >>= 1) {
      unsigned long long o = __shfl_xor(packed, off2, 64);
      if (o > packed) packed = o;
    }
    unsigned jw = 0xFFFFFFFFu - (unsigned)(packed & 0xFFFFFFFFull);
    if ((int)(jw & 63u) == lane) removed |= 1ull << (jw >> 6);
    if (t == lane) myj = jw;
  }
  if (lane < 20) atomicOr(&M[(size_t)i * 80 + (myj >> 5)], 1u << (myj & 31u));
}

// ---------- 4. symmetrize mask, build packed CSR (u16 col | bf16 W), D, dsi ----------
__global__ void k_csr(const unsigned short* __restrict__ C0,
                      const unsigned short* __restrict__ C1,
                      const unsigned short* __restrict__ C2,
                      const float* __restrict__ sq,
                      const unsigned* __restrict__ M, unsigned* __restrict__ csrG,
                      int* __restrict__ degG, float* __restrict__ dsi) {
  int i = blockIdx.x, t = threadIdx.x;
  __shared__ unsigned Mrow[80];
  __shared__ int degs;
  __shared__ unsigned packs[CAP];
  __shared__ float red[256];
  if (t < 80) Mrow[t] = M[(size_t)i * 80 + t];
  if (t == 0) degs = 0;
  __syncthreads();
  const unsigned short* r0c = C0 + (size_t)i * N;
  const unsigned short* r1c = C1 + (size_t)i * N;
  const unsigned short* r2c = C2 + (size_t)i * N;
  float sqi = sq[i];
  int iw = i >> 5; unsigned ib = 1u << (i & 31);
  float dsum = 0.f;
#pragma unroll
  for (int s = 0; s < 10; ++s) {
    int j = t + (s << 8);
    unsigned mij = (Mrow[j >> 5] >> (j & 31)) & 1u;
    unsigned mji = M[(size_t)j * 80 + iw] & ib;
    if (mij | (mji != 0u)) {
      float c = bf2f(r0c[j]) + bf2f(r1c[j]) + bf2f(r2c[j]);
      float wv = expf((2.f * c - sqi - sq[j]) * (1.f / 16384.f));
      int sl = atomicAdd(&degs, 1);
      if (sl < CAP) packs[sl] = (((unsigned)f2bf(wv)) << 16) | (unsigned)j;
      dsum += wv;
    }
  }
  red[t] = dsum; __syncthreads();
  for (int o = 128; o > 0; o >>= 1) { if (t < o) red[t] += red[t + o]; __syncthreads(); }
  if (t == 0) {
    degG[i] = degs > CAP ? CAP : degs;
    dsi[i] = 1.f / sqrtf(red[0] + EPSF);
  }
  __syncthreads();
  int dgc = degs > CAP ? CAP : degs;
  for (int sl = t; sl < dgc; sl += 256)
    csrG[(size_t)i * CAP + sl] = packs[sl];
}

// ---------- 5. merged: S edge scaling (in packed CSR) + Chebyshev init ----------
__global__ void k_scale_init(unsigned* __restrict__ csrG, const int* __restrict__ degG,
                             const float* __restrict__ dsi, const int* __restrict__ slab,
                             float* __restrict__ x, float* __restrict__ r,
                             unsigned short* __restrict__ d0) {
  int i = blockIdx.x * 4 + (threadIdx.x >> 6);
  int lane = threadIdx.x & 63;
  float di = dsi[i];
  int dg = degG[i];
  for (int s = lane; s < dg; s += 64) {
    unsigned p = csrG[(size_t)i * CAP + s];
    int j = p & 0xFFFFu;
    float wv = __uint_as_float(p & 0xFFFF0000u);
    wv *= di * dsi[j];
    csrG[(size_t)i * CAP + s] = (((unsigned)f2bf(wv)) << 16) | (unsigned)j;
  }
  int c0 = 2 * lane;
  float y0 = 0.f, y1 = 0.f;
  if (i < NSUP) {
    int lbl = slab[i];
    y0 = (lbl == c0) ? 1.f : 0.f;
    y1 = (lbl == c0 + 1) ? 1.f : 0.f;
  }
  size_t o = (size_t)i * NCLS + c0;
  x[o] = 0.f; x[o + 1] = 0.f;
  r[o] = y0;  r[o + 1] = y1;
  ushort2 dini; dini.x = f2bf(y0); dini.y = f2bf(y1);
  *(ushort2*)(d0 + o) = dini;
}

// ---------- 6. one Chebyshev iteration (A = I - alpha*S), d in bf16 ----------
// Champion structure (round 6/7, 16.2 us/iter): block per row, 256 threads,
// g = t&31 (4 classes), p = t>>5 (8 edge partitions), 8-deep unrolled gather.
__global__ __launch_bounds__(256) void k_cheby(const unsigned* __restrict__ csrG,
                        const int* __restrict__ degG, const float* __restrict__ rho_tab,
                        const float* __restrict__ alpha, float* __restrict__ x,
                        float* __restrict__ r, const unsigned short* __restrict__ dcur,
                        unsigned short* __restrict__ dnxt, int it) {
  int i = blockIdx.x;
  int t = threadIdx.x;
  int g4 = (t & 31) << 2, p = t >> 5;
  __shared__ unsigned lcv[CAP];
  __shared__ float4 partial[256];
  int dg = degG[i];
  for (int s = t; s < dg; s += 256) lcv[s] = csrG[(size_t)i * CAP + s];
  __syncthreads();
  float4 acc = make_float4(0.f, 0.f, 0.f, 0.f);
  int s = p;
  for (; s + 56 < dg; s += 64) {         // 8 partitions x 8-deep unroll
    unsigned uu[8]; ushort4 a[8];
#pragma unroll
    for (int u = 0; u < 8; ++u) {
      uu[u] = lcv[s + 8 * u];
      a[u] = *(const ushort4*)(dcur + (size_t)(uu[u] & 0xFFFFu) * NCLS + g4);
    }
#pragma unroll
    for (int u = 0; u < 8; ++u) {
      float v = __uint_as_float(uu[u] & 0xFFFF0000u);
      acc.x = fmaf(v, bf2f(a[u].x), acc.x);
      acc.y = fmaf(v, bf2f(a[u].y), acc.y);
      acc.z = fmaf(v, bf2f(a[u].z), acc.z);
      acc.w = fmaf(v, bf2f(a[u].w), acc.w);
    }
  }
  for (; s < dg; s += 8) {               // tail
    unsigned uu = lcv[s];
    ushort4 a = *(const ushort4*)(dcur + (size_t)(uu & 0xFFFFu) * NCLS + g4);
    float v = __uint_as_float(uu & 0xFFFF0000u);
    acc.x = fmaf(v, bf2f(a.x), acc.x); acc.y = fmaf(v, bf2f(a.y), acc.y);
    acc.z = fmaf(v, bf2f(a.z), acc.z); acc.w = fmaf(v, bf2f(a.w), acc.w);
  }
  partial[t] = acc;
  __syncthreads();
  for (int off = 128; off >= 32; off >>= 1) {
    if (t < off) {
      float4 o = partial[t + off];
      float4 m = partial[t];
      m.x += o.x; m.y += o.y; m.z += o.z; m.w += o.w;
      partial[t] = m;
    }
    __syncthreads();
  }
  if (t < 32) {                          // classes 4t..4t+3
    float4 ax = partial[t];
    float ahat = alpha[0];
    float rho = rho_tab[it], rhon = rho_tab[it + 1];
    float cc1 = rhon * rho, cc2 = 2.f * rhon / ahat;
    size_t o = (size_t)i * NCLS + 4 * t;
    ushort4 dv = *(const ushort4*)(dcur + o);
    float4 di; di.x = bf2f(dv.x); di.y = bf2f(dv.y); di.z = bf2f(dv.z); di.w = bf2f(dv.w);
    float4 xv = *(float4*)(x + o);
    float4 rv = *(float4*)(r + o);
    float4 q;
    q.x = di.x - ahat * ax.x; q.y = di.y - ahat * ax.y;
    q.z = di.z - ahat * ax.z; q.w = di.w - ahat * ax.w;
    xv.x += di.x; xv.y += di.y; xv.z += di.z; xv.w += di.w;
    rv.x -= q.x; rv.y -= q.y; rv.z -= q.z; rv.w -= q.w;
    ushort4 dn;
    dn.x = f2bf(cc1 * di.x + cc2 * rv.x); dn.y = f2bf(cc1 * di.y + cc2 * rv.y);
    dn.z = f2bf(cc1 * di.z + cc2 * rv.z); dn.w = f2bf(cc1 * di.w + cc2 * rv.w);
    *(float4*)(x + o) = xv;
    *(float4*)(r + o) = rv;
    *(ushort4*)(dnxt + o) = dn;
  }
}

// ---------- 7. loss + acc ----------
__global__ void k_loss(const float* __restrict__ F, const int* __restrict__ slab,
                       const int* __restrict__ qlab, float* __restrict__ lossSum,
                       int* __restrict__ accCnt) {
  int i = blockIdx.x * 4 + (threadIdx.x >> 6);
  int lane = threadIdx.x & 63;
  int c0 = 2 * lane;
  float2 f = *(const float2*)(F + (size_t)i * NCLS + c0);
  float mx = fmaxf(f.x, f.y);
  for (int o2 = 32; o2 > 0; o2 >>= 1) mx = fmaxf(mx, __shfl_xor(mx, o2, 64));
  float se = expf(f.x - mx) + expf(f.y - mx);
  for (int o2 = 32; o2 > 0; o2 >>= 1) se += __shfl_xor(se, o2, 64);
  float lse = mx + logf(se);
  int gt = (i < NSUP) ? slab[i] : qlab[i - NSUP];
  float fg = ((c0 == gt) ? f.x : 0.f) + ((c0 + 1 == gt) ? f.y : 0.f);
  for (int o2 = 32; o2 > 0; o2 >>= 1) fg += __shfl_xor(fg, o2, 64);
  if (lane == 0) atomicAdd(lossSum, fg - lse);
  if (i >= NSUP) {
    float bvv; int bc;
    if (f.y > f.x) { bvv = f.y; bc = c0 + 1; } else { bvv = f.x; bc = c0; }
    unsigned long long packed =
        (((unsigned long long)sortkey(bvv)) << 32) | (unsigned long long)(unsigned)(127 - bc);
    for (int o2 = 32; o2 > 0; o2 >>= 1) {
      unsigned long long o = __shfl_xor(packed, o2, 64);
      if (o > packed) packed = o;
    }
    int cw = 127 - (int)(packed & 0xFFFFFFFFull);
    if (lane == 0 && cw == qlab[i - NSUP]) atomicAdd(accCnt, 1);
  }
}

// ---------- 8. finalize ----------
__global__ void k_final(const float* __restrict__ lossSum, const int* __restrict__ accCnt,
                        float* __restrict__ out) {
  out[0] = -lossSum[0] / (float)N;
  out[1] = (float)accCnt[0] / (float)NQ;
}

// ---------- launch ----------
extern "C" void kernel_launch(void* const* d_in, const int* in_sizes, int n_in,
                              void* d_out, int out_size, void* d_ws, size_t ws_size,
                              hipStream_t stream) {
  const float* feats = (const float*)d_in[0];
  const float* alpha = (const float*)d_in[1];
  const int* slab = (const int*)d_in[2];
  const int* qlab = (const int*)d_in[3];
  float* out = (float*)d_out;
  char* ws = (char*)d_ws;

  // ws layout (bytes). C0/C1/C2 (bf16, 13,107,200 each) die after k_csr;
  // x/r/d0/d1 overlay C0. csrG overlays fb8 after k_gemm.
  unsigned short* C0 = (unsigned short*)(ws + 0);
  unsigned short* C1 = (unsigned short*)(ws + 13107200);
  unsigned short* C2 = (unsigned short*)(ws + 26214400);
  float* x           = (float*)(ws + 0);
  float* r           = (float*)(ws + 1310720);
  unsigned short* d0 = (unsigned short*)(ws + 2621440);   // bf16, 655,360 B
  unsigned short* d1 = (unsigned short*)(ws + 3276800);   // bf16, 655,360 B
  unsigned* M   = (unsigned*)(ws + 39321600);          // 819,200 B bitmask
  float* ctrl   = (float*)(ws + 40140800);             // lossSum, accCnt, rho_tab
  float* lossSum = ctrl;
  int* accCnt   = (int*)(ctrl + 1);
  float* rho_tab = ctrl + 4;                           // 128 floats
  float* sq     = (float*)(ws + 40141824);
  float* dsi    = (float*)(ws + 40152064);
  int* degG     = (int*)(ws + 40162304);
  unsigned char* fb8 = (unsigned char*)(ws + 40172544);   // 20,971,520 B fp8 feats
  unsigned* csrG = (unsigned*)(ws + 40172544);            // overlays fb8 after GEMM
  // total ws required: 61,144,064 bytes

  hipMemsetAsync(ws + 39321600, 0, 820224, stream);    // M + ctrl
  k_prep<<<N, 256, 0, stream>>>(feats, fb8, sq, alpha, rho_tab);
  k_gemm<<<630, 256, 0, stream>>>(fb8, C0, C1, C2);    // lower-tri tiles, split-K x3
  k_topk<<<N / 4, 256, 0, stream>>>(C0, C1, C2, sq, M);
  k_csr<<<N, 256, 0, stream>>>(C0, C1, C2, sq, M, csrG, degG, dsi);
  k_scale_init<<<N / 4, 256, 0, stream>>>(csrG, degG, dsi, slab, x, r, d0);
  for (int it = 0; it < TITER; ++it) {
    const unsigned short* dc = (it & 1) ? d1 : d0;
    unsigned short* dn = (it & 1) ? d0 : d1;
    k_cheby<<<N, 256, 0, stream>>>(csrG, degG, rho_tab, alpha, x, r, dc, dn, it);
  }
  k_loss<<<N / 4, 256, 0, stream>>>(x, slab, qlab, lossSum, accCnt);
  k_final<<<1, 1, 0, stream>>>(lossSum, accCnt, out);
}